// Round 9
// baseline (327.779 us; speedup 1.0000x reference)
//
#include <hip/hip_runtime.h>
#include <hip/hip_bf16.h>
#include <cstdint>

// Problem dims (fixed by reference setup_inputs)
constexpr int Bc  = 2;
constexpr int Lc  = 4096;
constexpr int Hc  = 2048;
constexpr int LKc = 128;
constexpr float LAMc = 0.003f;

typedef __attribute__((ext_vector_type(8))) __bf16 bf16x8;
typedef __attribute__((ext_vector_type(4))) float  f32x4;
typedef __attribute__((ext_vector_type(8))) unsigned short ushort8;

__device__ __forceinline__ unsigned short f2bf_bits(float v) {
  union { __hip_bfloat16 b; unsigned short u; } cv;
  cv.b = __float2bfloat16(v);
  return cv.u;
}
__device__ __forceinline__ float bf_bits2f(unsigned short u) {
  union { unsigned int i; float f; } cv;
  cv.i = ((unsigned int)u) << 16;
  return cv.f;
}

// ---------------------------------------------------------------------------
// async global->LDS, 16B per lane. LDS dest is the WAVE-UNIFORM base; HW adds
// lane*16. Global src is per-lane (pre-gathered fragment order).
// ---------------------------------------------------------------------------
__device__ __forceinline__ void gl_lds16(const void* g, void* lds) {
  __builtin_amdgcn_global_load_lds(
      (const __attribute__((address_space(1))) uint32_t*)(uintptr_t)g,
      (__attribute__((address_space(3))) uint32_t*)(uint32_t)(uintptr_t)lds,
      16, 0, 0);
}

// ---------------------------------------------------------------------------
// Kernel 1: tap squash + Hankel MFMA A-fragment precompute (unchanged).
// ---------------------------------------------------------------------------
__global__ __launch_bounds__(256) void tapfrag_kernel(
    const float* __restrict__ kin, unsigned short* __restrict__ Afr) {
  const int idx  = blockIdx.x * 256 + threadIdx.x;  // [0, 2048*5*64)
  const int lane = idx & 63;
  const int idx2 = idx >> 6;          // h*5 + cc
  const int h  = idx2 / 5;
  const int cc = idx2 - h * 5;
  const int m = lane & 15, quad = lane >> 4;
  const int jb = m + 32 * cc - 32 + 8 * quad;
  ushort8 o;
#pragma unroll
  for (int jj = 0; jj < 8; ++jj) {
    const int j = jb + jj;
    float v = 0.f;
    if (j >= 0 && j < LKc) {
      const float x = kin[h * LKc + j];
      const float a = fabsf(x) - LAMc;
      v = (a > 0.f) ? copysignf(a, x) : 0.f;
    }
    o[jj] = f2bf_bits(v);
  }
  ((ushort8*)Afr)[idx] = o;
}

// ---------------------------------------------------------------------------
// Kernel 2: W fp32 [2H, H] -> bf16 same layout (unchanged).
// ---------------------------------------------------------------------------
__global__ __launch_bounds__(256) void wcast_kernel(
    const float* __restrict__ W, __hip_bfloat16* __restrict__ Wb) {
  const int idx = (blockIdx.x * 256 + threadIdx.x) * 4;
  const float4 v = *(const float4*)(W + idx);
  Wb[idx + 0] = __float2bfloat16(v.x);
  Wb[idx + 1] = __float2bfloat16(v.y);
  Wb[idx + 2] = __float2bfloat16(v.z);
  Wb[idx + 3] = __float2bfloat16(v.w);
}

// ---------------------------------------------------------------------------
// Kernel 3 (v4): MFMA FIR conv.
//  - float4 staging (r6-verified win), processed as x-PAIRS so LDS writes
//    are packed ds_write_b32: write instrs 44->20/thread, 11->6 iters, and
//    staging bank aliasing drops 4-way -> 2-way (free).
//  - Afr prefetch + tanh GELU kept (r7: neutral, harmless).
// ---------------------------------------------------------------------------
__global__ __launch_bounds__(256) void conv_mfma_kernel(
    const float* __restrict__ u, const unsigned short* __restrict__ Afr,
    const float* __restrict__ Dp, unsigned short* __restrict__ Am) {
  __shared__ __align__(16) unsigned short ur[16 * 664];  // 21248 B
  __shared__ __align__(16) unsigned short ot[512 * 17];  // 17408 B

  const int t    = threadIdx.x;
  const int lane = t & 63;
  const int wv   = t >> 6;
  const int l16  = lane & 15;
  const int quad = lane >> 4;
  const int l0 = blockIdx.x * 512;
  const int h0 = blockIdx.y * 16;
  const int b  = blockIdx.z;

  const size_t ubase = (size_t)b * Lc * Hc + h0;

  // ---- Afr prefetch for hi=0: issued before staging, lands during it
  const unsigned short* afp0 =
      Afr + ((size_t)((h0 + (wv << 2)) * 5) * 64 + lane) * 8;
  bf16x8 afc[5];
#pragma unroll
  for (int cc = 0; cc < 5; ++cc) afc[cc] = *(const bf16x8*)(afp0 + cc * 512);

  // ---- stage 16 h x 656 l (reversed, bf16): 328 x-pairs x 4 hq = 1312 units
#pragma unroll
  for (int i = 0; i < 6; ++i) {
    const int e = i * 256 + t;
    if (e < 1312) {
      const int xp = e >> 2;          // x = 2xp, 2xp+1  (0..327)
      const int hq = (e & 3) << 2;    // 0,4,8,12
      const int l  = l0 + 528 - 2 * xp;
      float4 v0 = make_float4(0.f, 0.f, 0.f, 0.f);
      float4 v1 = make_float4(0.f, 0.f, 0.f, 0.f);
      if (l >= 0)
        v0 = *(const float4*)(u + ubase + (size_t)min(l, Lc - 1) * Hc + hq);
      if (l - 1 >= 0)
        v1 = *(const float4*)(u + ubase + (size_t)min(l - 1, Lc - 1) * Hc + hq);
      const float va[4] = {v0.x, v0.y, v0.z, v0.w};
      const float vb[4] = {v1.x, v1.y, v1.z, v1.w};
#pragma unroll
      for (int j = 0; j < 4; ++j) {
        const unsigned int pk =
            (unsigned int)f2bf_bits(va[j]) | ((unsigned int)f2bf_bits(vb[j]) << 16);
        *(unsigned int*)&ur[(hq + j) * 664 + 2 * xp] = pk;
      }
    }
  }
  __syncthreads();

#pragma unroll 1
  for (int hi = 0; hi < 4; ++hi) {
    const int hl = (wv << 2) | hi;
    const int h  = h0 + hl;
    // prefetch next hi's taps; latency overlaps this hi's MFMA cluster
    bf16x8 afn[5];
    if (hi < 3) {
      const unsigned short* afp = afp0 + (size_t)(hi + 1) * 5 * 512;
#pragma unroll
      for (int cc = 0; cc < 5; ++cc) afn[cc] = *(const bf16x8*)(afp + cc * 512);
    }
    const float dv = 2.f * Dp[h];
    const unsigned short* urh = &ur[hl * 664];
#pragma unroll
    for (int nt = 0; nt < 2; ++nt) {
      f32x4 acc = f32x4{0.f, 0.f, 0.f, 0.f};
      const int bbase = 496 - 256 * nt - 16 * l16 + 8 * quad;
#pragma unroll
      for (int cc = 0; cc < 5; ++cc) {
        const bf16x8 bf = *(const bf16x8*)(urh + bbase + 32 * cc);
        acc = __builtin_amdgcn_mfma_f32_16x16x32_bf16(afc[cc], bf, acc, 0, 0, 0);
      }
#pragma unroll
      for (int r = 0; r < 4; ++r) {
        const int lc = quad * 4 + r + 16 * l16;
        const float uu = bf_bits2f(urh[528 - 256 * nt - lc]);
        const float y = fmaf(dv, uu, acc[r]);
        // GELU (tanh form): y * sigmoid(y*(1.5957691 + 0.07135482*y^2))
        const float z = y * fmaf(0.07135481627f, y * y, 1.5957691216f);
        const float g = y * __builtin_amdgcn_rcpf(1.f + __expf(-z));
        ot[(nt * 256 + lc) * 17 + hl] = f2bf_bits(g);
      }
    }
    if (hi < 3) {
#pragma unroll
      for (int cc = 0; cc < 5; ++cc) afc[cc] = afn[cc];
    }
  }
  __syncthreads();

#pragma unroll
  for (int rr = 0; rr < 2; ++rr) {
    const int lc = (rr << 8) + t;
    const unsigned short* row = &ot[lc * 17];
    unsigned int w[8];
#pragma unroll
    for (int p = 0; p < 8; ++p)
      w[p] = (unsigned int)row[2 * p] | ((unsigned int)row[2 * p + 1] << 16);
    unsigned short* dst = Am + ((size_t)(b * Lc + l0 + lc)) * Hc + h0;
    *(uint4*)(dst)     = make_uint4(w[0], w[1], w[2], w[3]);
    *(uint4*)(dst + 8) = make_uint4(w[4], w[5], w[6], w[7]);
  }
}

// ---------------------------------------------------------------------------
// Kernel 4 (v5 + bofs split): latency-tolerant GEMM + bias + GLU.
//  - identical math/schedule to r5-verified v5; bid = blockIdx.x + bofs so the
//    512-block space is covered by TWO 256-block dispatches. (b+256)&7 == b&7
//    -> XCD remap and all addressing bit-identical. Purpose: halve per-dispatch
//    dur so conv_mfma surfaces in the rocprof top-5 next round.
// ---------------------------------------------------------------------------
constexpr int KTILES = Hc / 32;  // 64

__global__ __launch_bounds__(512, 2) void gemm_glu_kernel(
    const __hip_bfloat16* __restrict__ A, const __hip_bfloat16* __restrict__ Wb,
    const float* __restrict__ bias, float* __restrict__ out, int bofs) {
  __shared__ __align__(16) char lds[131072];  // 4 slots x (A 16KB + B 16KB)

  const int t    = threadIdx.x;
  const int lane = t & 63;
  const int w    = t >> 6;        // wave 0..7
  const int l16  = lane & 15;
  const int quad = lane >> 4;
  const int wr   = w >> 2;        // 0..1 : M band
  const int wc   = w & 3;         // 0..3 : N band

  // bijective XCD-locality remap: xcd = bid&7 (HW round-robin), s = bid>>3.
  const int bid = blockIdx.x + bofs;  // 0..511
  const int xcd = bid & 7;
  const int s   = bid >> 3;       // 0..63
  const int m0g = (xcd * 4 + (s >> 4)) * 256;
  const int n0  = (s & 15) * 128;

  // per-thread pre-gathered staging sources: idx 0,1 = A units, 2,3 = B units
  const __hip_bfloat16* gsrc[4];
#pragma unroll
  for (int u = 0; u < 2; ++u) {
    const int f = u * 8 + w;  // fragment index 0..15 staged by this wave
    gsrc[u] = A + (size_t)(m0g + f * 16 + l16) * Hc + quad * 8;
    const int wrow = ((f >> 1) & 1) * Hc + n0 + (f >> 2) * 32 + (f & 1) * 16 + l16;
    gsrc[2 + u] = Wb + (size_t)wrow * Hc + quad * 8;
  }

  f32x4 acc[8][4];
#pragma unroll
  for (int i = 0; i < 8; ++i)
#pragma unroll
    for (int j = 0; j < 4; ++j) acc[i][j] = f32x4{0.f, 0.f, 0.f, 0.f};

// wave-uniform LDS dest: slot + region + frag run; HW adds lane*16
#define STAGE(tile, idx)                                                      \
  gl_lds16(gsrc[idx] + (size_t)(tile) * 32,                                   \
           lds + ((tile) & 3) * 32768 + (((idx) >> 1) & 1) * 16384 +          \
               (((idx) & 1) * 8 + w) * 1024)

  // prologue: K-tiles 0,1,2 (4 loads/lane each, 12 outstanding)
#pragma unroll
  for (int i = 0; i < 4; ++i) STAGE(0, i);
#pragma unroll
  for (int i = 0; i < 4; ++i) STAGE(1, i);
#pragma unroll
  for (int i = 0; i < 4; ++i) STAGE(2, i);
  asm volatile("s_waitcnt vmcnt(8)" ::: "memory");  // tile 0 landed
  __builtin_amdgcn_s_barrier();

  const char* sAbase = lds + wr * 8192 + lane * 16;
  const char* sBbase = lds + 16384 + wc * 4096 + lane * 16;

  // One BK=32 K-tile: {12 ds_read || 4 stage(kt+3) || 32 MFMA} -> vmcnt(N)
  // -> barrier.  Steady-state VMN=8 (tiles kt+2,kt+3 in flight; kt+1 landed).
#define KTILE_BODY(KT, DO_STAGE, VMN)                                         \
  {                                                                           \
    const char* sA = sAbase + ((KT) & 3) * 32768;                             \
    const char* sB = sBbase + ((KT) & 3) * 32768;                             \
    bf16x8 afr[8], bfr[4];                                                    \
    _Pragma("unroll") for (int i = 0; i < 4; ++i)                             \
        bfr[i] = *(const bf16x8*)(sB + i * 1024);                             \
    _Pragma("unroll") for (int i = 0; i < 8; ++i)                             \
        afr[i] = *(const bf16x8*)(sA + i * 1024);                             \
    if (DO_STAGE) {                                                           \
      STAGE((KT) + 3, 0); STAGE((KT) + 3, 1);                                 \
      STAGE((KT) + 3, 2); STAGE((KT) + 3, 3);                                 \
    }                                                                         \
    __builtin_amdgcn_s_setprio(1);                                            \
    _Pragma("unroll") for (int mf = 0; mf < 8; ++mf)                          \
        _Pragma("unroll") for (int nf = 0; nf < 4; ++nf)                      \
            acc[mf][nf] = __builtin_amdgcn_mfma_f32_16x16x32_bf16(            \
                afr[mf], bfr[nf], acc[mf][nf], 0, 0, 0);                      \
    __builtin_amdgcn_s_setprio(0);                                            \
    asm volatile("s_waitcnt vmcnt(" #VMN ")" ::: "memory");                   \
    __builtin_amdgcn_s_barrier();                                             \
  }

  // main loop: tiles 0..59 (unroll 4 folds slot offsets), staging kt+3
#pragma unroll 1
  for (int k4 = 0; k4 < 15; ++k4) {
    const int kt = k4 * 4;
    KTILE_BODY(kt + 0, true, 8)
    KTILE_BODY(kt + 1, true, 8)
    KTILE_BODY(kt + 2, true, 8)
    KTILE_BODY(kt + 3, true, 8)
  }
  // tail: tile 60 stages 63 (last); then drain 8 -> 4 -> 0
  KTILE_BODY(60, true, 8)
  KTILE_BODY(61, false, 4)
  KTILE_BODY(62, false, 0)
  KTILE_BODY(63, false, 0)
#undef KTILE_BODY
#undef STAGE

  // ---------- epilogue: lane-local GLU (a at nf, g at nf+2), coalesced rows
  const int mwb = m0g + wr * 128 + quad * 4;
  const int nb  = n0 + wc * 32 + l16;
#pragma unroll
  for (int j = 0; j < 2; ++j) {
    const int n = nb + j * 16;
    const float ba = bias[n];
    const float bg = bias[Hc + n];
#pragma unroll
    for (int mf = 0; mf < 8; ++mf) {
#pragma unroll
      for (int r = 0; r < 4; ++r) {
        const float a = acc[mf][j][r] + ba;
        const float g = acc[mf][j + 2][r] + bg;
        out[(size_t)(mwb + mf * 16 + r) * Hc + n] = a * (1.f / (1.f + expf(-g)));
      }
    }
  }
}

// ---------------------------------------------------------------------------
extern "C" void kernel_launch(void* const* d_in, const int* in_sizes, int n_in,
                              void* d_out, int out_size, void* d_ws, size_t ws_size,
                              hipStream_t stream) {
  const float* u    = (const float*)d_in[0];  // [B, L, H]
  const float* kin  = (const float*)d_in[1];  // [1, H, LK]
  const float* Dp   = (const float*)d_in[2];  // [1, H]
  const float* W    = (const float*)d_in[3];  // [2H, H]
  const float* bias = (const float*)d_in[4];  // [2H]
  float* out = (float*)d_out;                 // [B, L, H]

  // ws layout:
  //   [0, 10.5MB)  Afr  (tap fragments; dead after conv)
  //   [0, 16MB)    Wb   (bf16 W; written AFTER conv reads Afr -- same stream)
  //   [16MB, 48MB) Am   (bf16 activations)
  char* ws = (char*)d_ws;
  unsigned short* Afr = (unsigned short*)ws;
  __hip_bfloat16* Wb  = (__hip_bfloat16*)ws;
  unsigned short* Am  = (unsigned short*)(ws + (16 << 20));

  tapfrag_kernel<<<(Hc * 5 * 64) / 256, 256, 0, stream>>>(kin, Afr);
  conv_mfma_kernel<<<dim3(Lc / 512, Hc / 16, Bc), 256, 0, stream>>>(u, Afr, Dp, Am);
  wcast_kernel<<<(2 * Hc * Hc) / 1024, 256, 0, stream>>>(W, Wb);
  gemm_glu_kernel<<<256, 512, 0, stream>>>(
      (const __hip_bfloat16*)Am, Wb, bias, out, 0);
  gemm_glu_kernel<<<256, 512, 0, stream>>>(
      (const __hip_bfloat16*)Am, Wb, bias, out, 256);
}